// Round 2
// baseline (84.420 us; speedup 1.0000x reference)
//
#include <hip/hip_runtime.h>

#define N 64
#define MARGIN 0.1f
#define WAVES_PER_BLOCK 4
#define NBLOCKS 2048

// closed form (verified R2..R11, absmax 0.0): row_loss = sum_e u_e*(q_e - p_e)
//   p_e = #{k: lab_k < lab_e},  u_e = sc_e - MARGIN*p_e,  q_e = #{k: u_k < u_e}
//
// R13 (= R12 with compile fix): wave-collective ballot ranking.
//   Old (R11): each lane counts its own rank -> 3 VALU/cmp (v_sub, v_ashr, v_add).
//   New: iteration k compares ALL lanes against broadcast elem_k with one
//        v_cmp (writes sgpr pair), popcount on the FREE scalar pipe
//        (s_bcnt1_i32_b64), one v_writelane_b32 delivers rank to lane k.
//        => 2 VALU-class ops/element, 64 v_cmp/pass = minimum possible.
//   __builtin_amdgcn_writelane is not declared in these HIP headers ->
//   inline asm v_writelane_b32 ("s" count, "i" lane imm; loop fully unrolled
//   so lane indices are compile-time constants; non-volatile so the
//   scheduler can interleave the two independent row chains).
//   2-row software pipelining: independent cmp/bcnt/writelane chains,
//   double-slotted ubuf, one lgkm drain per row-pair.

#define RANK1(dst, val, elem, k)                                    \
    do {                                                            \
        const int _cnt = (int)__popcll(__ballot((val) < (elem)));   \
        asm("v_writelane_b32 %0, %1, %2"                            \
            : "+v"(dst)                                             \
            : "s"(_cnt), "i"(k));                                   \
    } while (0)

#define RANK4(dst, val, a, k0)            \
    do {                                  \
        RANK1(dst, val, (a).x, (k0) + 0); \
        RANK1(dst, val, (a).y, (k0) + 1); \
        RANK1(dst, val, (a).z, (k0) + 2); \
        RANK1(dst, val, (a).w, (k0) + 3); \
    } while (0)

__global__ __launch_bounds__(256) void mmrl_partial(const float* __restrict__ scores,
                                                    const float* __restrict__ labels,
                                                    float* __restrict__ partial,
                                                    int rows) {
    __shared__ float ubuf[WAVES_PER_BLOCK][2][N];
    __shared__ float wsum[WAVES_PER_BLOCK];

    const int lane = threadIdx.x & 63;
    const int w    = threadIdx.x >> 6;
    const int gwave = blockIdx.x * WAVES_PER_BLOCK + w;
    const int nwaves = NBLOCKS * WAVES_PER_BLOCK;

    float acc = 0.0f;

    int row = gwave;

    // ---- paired rows: independent chains for ILP, one lgkm drain per pair ----
    for (; row + nwaves < rows; row += 2 * nwaves) {
        const int base0 = __builtin_amdgcn_readfirstlane(row) * N;
        const int base1 = base0 + nwaves * N;

        const float labv0 = labels[base0 + lane];   // coalesced per-lane copy
        const float scv0  = scores[base0 + lane];
        const float labv1 = labels[base1 + lane];
        const float scv1  = scores[base1 + lane];

        const float4* L40 = (const float4*)(labels + base0);  // uniform broadcasts
        const float4* L41 = (const float4*)(labels + base1);

        // ---- pass 1: label ranks p (ballot + scalar popcount + writelane) ----
        int p0 = 0, p1 = 0;
        #pragma unroll
        for (int kk = 0; kk < N / 4; ++kk) {
            const float4 a0 = L40[kk];
            RANK4(p0, labv0, a0, 4 * kk);
            const float4 a1 = L41[kk];
            RANK4(p1, labv1, a1, 4 * kk);
        }

        const float u0 = fmaf(-MARGIN, (float)p0, scv0);
        const float u1 = fmaf(-MARGIN, (float)p1, scv1);
        ubuf[w][0][lane] = u0;
        ubuf[w][1][lane] = u1;
        asm volatile("s_waitcnt lgkmcnt(0)" ::: "memory");  // intra-wave LDS in-order

        // ---- pass 2: u ranks q (LDS uniform float4 broadcasts) ----
        const float4* U40 = (const float4*)ubuf[w][0];
        const float4* U41 = (const float4*)ubuf[w][1];
        int q0 = 0, q1 = 0;
        #pragma unroll
        for (int kk = 0; kk < N / 4; ++kk) {
            const float4 b0 = U40[kk];
            RANK4(q0, u0, b0, 4 * kk);
            const float4 b1 = U41[kk];
            RANK4(q1, u1, b1, 4 * kk);
        }

        acc = fmaf(u0, (float)(q0 - p0), acc);
        acc = fmaf(u1, (float)(q1 - p1), acc);
    }

    // ---- tail: single row (generic; not hit for rows=32768, nwaves=8192) ----
    for (; row < rows; row += nwaves) {
        const int base = __builtin_amdgcn_readfirstlane(row) * N;
        const float labv = labels[base + lane];
        const float scv  = scores[base + lane];
        const float4* L4 = (const float4*)(labels + base);

        int p = 0;
        #pragma unroll
        for (int kk = 0; kk < N / 4; ++kk) {
            const float4 a = L4[kk];
            RANK4(p, labv, a, 4 * kk);
        }

        const float u = fmaf(-MARGIN, (float)p, scv);
        ubuf[w][0][lane] = u;
        asm volatile("s_waitcnt lgkmcnt(0)" ::: "memory");

        const float4* U4 = (const float4*)ubuf[w][0];
        int q = 0;
        #pragma unroll
        for (int kk = 0; kk < N / 4; ++kk) {
            const float4 b = U4[kk];
            RANK4(q, u, b, 4 * kk);
        }

        acc = fmaf(u, (float)(q - p), acc);
    }

    // ---- wave reduction ----
    #pragma unroll
    for (int off = 32; off > 0; off >>= 1)
        acc += __shfl_down(acc, off, 64);

    if (lane == 0) wsum[w] = acc;
    __syncthreads();
    if (threadIdx.x == 0) {
        float s = 0.0f;
        #pragma unroll
        for (int i = 0; i < WAVES_PER_BLOCK; ++i) s += wsum[i];
        partial[blockIdx.x] = s;          // plain store, no atomic, no fence
    }
}

__global__ __launch_bounds__(256) void mmrl_reduce(const float* __restrict__ partial,
                                                   float* __restrict__ out,
                                                   int npartial, float inv_rows) {
    const int t = threadIdx.x;
    float s = 0.0f;
    for (int i = t; i < npartial; i += 256)
        s += partial[i];
    #pragma unroll
    for (int off = 32; off > 0; off >>= 1)
        s += __shfl_down(s, off, 64);
    __shared__ float wsum[4];
    if ((t & 63) == 0) wsum[t >> 6] = s;
    __syncthreads();
    if (t == 0)
        out[0] = (wsum[0] + wsum[1] + wsum[2] + wsum[3]) * inv_rows;
}

extern "C" void kernel_launch(void* const* d_in, const int* in_sizes, int n_in,
                              void* d_out, int out_size, void* d_ws, size_t ws_size,
                              hipStream_t stream) {
    const float* scores = (const float*)d_in[0];
    const float* labels = (const float*)d_in[1];
    float* out = (float*)d_out;
    float* partial = (float*)d_ws;        // 2048 floats = 8 KB << ws_size
    const int rows = in_sizes[0] / N;     // 32768

    mmrl_partial<<<NBLOCKS, 256, 0, stream>>>(scores, labels, partial, rows);
    mmrl_reduce<<<1, 256, 0, stream>>>(partial, out, NBLOCKS, 1.0f / (float)rows);
}